// Round 15
// baseline (402.129 us; speedup 1.0000x reference)
//
#include <hip/hip_runtime.h>

#define NN 50000
#define NE 1600000
#define CLAMP_V 5.0f
#define NB 2048                    // phase-1 chunks
#define CH ((NE + NB - 1) / NB)    // 782 edges per chunk
#define BSHIFT 9                   // 512 nodes per bucket
#define NBUCK ((NN + (1 << BSHIFT) - 1) >> BSHIFT)   // 98
#define BPAD 128
#define PROJ_BLOCKS 1024
#define ESTR 68                    // padded Elds row stride (floats)

typedef __attribute__((ext_vector_type(4))) short bf16x4;
typedef __attribute__((ext_vector_type(4))) float f32x4;

static __device__ __forceinline__ short f2bf(float x) {
    unsigned u = __builtin_bit_cast(unsigned, x);
    u += 0x7FFF + ((u >> 16) & 1);   // round-to-nearest-even
    return (short)(u >> 16);
}

// Fused: blocks [0,NB) do the dst histogram; blocks [NB, NB+PROJ_BLOCKS) do
// the Q/K/V projection. Single launch -> both run concurrently on the GPU.
__global__ __launch_bounds__(256) void histproj_kernel(
    const int* __restrict__ ei, int* __restrict__ blockHist,
    const float* __restrict__ x,
    const float* __restrict__ WQ, const float* __restrict__ bQ,
    const float* __restrict__ WK, const float* __restrict__ WVw,
    float* __restrict__ Q, float* __restrict__ K, float* __restrict__ V)
{
    __shared__ float sW[3 * 4096];
    if (blockIdx.x < NB) {
        int* h = (int*)sW;
        if (threadIdx.x < BPAD) h[threadIdx.x] = 0;
        __syncthreads();
        const int b  = blockIdx.x;
        const int e0 = b * CH;
        const int e1 = (e0 + CH < NE) ? e0 + CH : NE;
        for (int e = e0 + threadIdx.x; e < e1; e += 256)
            atomicAdd(&h[ei[NE + e] >> BSHIFT], 1);
        __syncthreads();
        if (threadIdx.x < NBUCK) blockHist[b * BPAD + threadIdx.x] = h[threadIdx.x];
        return;
    }
    // ---- projection path ----
    float* sWQ = sW;
    float* sWK = sW + 4096;
    float* sWV = sW + 8192;
    for (int i = threadIdx.x; i < 4096; i += 256) {
        sWQ[i] = WQ[i]; sWK[i] = WK[i]; sWV[i] = WVw[i];
    }
    __syncthreads();
    const int col = threadIdx.x & 63;
    const int nl  = threadIdx.x >> 6;
    const float bq = bQ[col];
    const int pb  = blockIdx.x - NB;
    for (int node = pb * 4 + nl; node < NN; node += PROJ_BLOCKS * 4) {
        const float* xr = x + (size_t)node * 64;
        float aq = 0.f, ak = 0.f, av = 0.f;
        #pragma unroll
        for (int j = 0; j < 64; ++j) {
            float xv = xr[j];
            aq = fmaf(xv, sWQ[j*64+col], aq);
            ak = fmaf(xv, sWK[j*64+col], ak);
            av = fmaf(xv, sWV[j*64+col], av);
        }
        Q[(size_t)node*64+col] = aq + bq;
        K[(size_t)node*64+col] = ak;
        V[(size_t)node*64+col] = av;
    }
}

__global__ __launch_bounds__(64) void scanA_kernel(
    int* __restrict__ blockHist, int* __restrict__ bucketTotal)
{
    const int k    = blockIdx.x;
    const int lane = threadIdx.x;
    int running = 0;
    for (int c = 0; c < NB; c += 64) {
        int v = blockHist[(c + lane) * BPAD + k];
        int incl = v;
        #pragma unroll
        for (int d = 1; d < 64; d <<= 1) {
            int t = __shfl_up(incl, d);
            if (lane >= d) incl += t;
        }
        blockHist[(c + lane) * BPAD + k] = running + (incl - v);
        running += __shfl(incl, 63);
    }
    if (lane == 0) bucketTotal[k] = running;
}

// wave-parallel exclusive scan of the 98 bucket totals (was 1-thread serial)
__global__ __launch_bounds__(64) void scanB_kernel(
    const int* __restrict__ bucketTotal, int* __restrict__ bucketStart)
{
    const int lane = threadIdx.x;
    int carry = 0;
    for (int base = 0; base <= NBUCK; base += 64) {
        const int idx = base + lane;
        int v = (idx < NBUCK) ? bucketTotal[idx] : 0;
        int incl = v;
        #pragma unroll
        for (int d = 1; d < 64; d <<= 1) {
            int t = __shfl_up(incl, d);
            if (lane >= d) incl += t;
        }
        if (idx <= NBUCK) bucketStart[idx] = carry + incl - v;
        carry += __shfl(incl, 63);
    }
}

__global__ __launch_bounds__(256) void scatter1_kernel(
    const int* __restrict__ ei, const int* __restrict__ blockHist,
    const int* __restrict__ bucketStart, uint2* __restrict__ binned)
{
    __shared__ int cur[BPAD];
    const int b = blockIdx.x;
    if (threadIdx.x < NBUCK)
        cur[threadIdx.x] = bucketStart[threadIdx.x] + blockHist[b * BPAD + threadIdx.x];
    __syncthreads();
    const int e0 = b * CH;
    const int e1 = (e0 + CH < NE) ? e0 + CH : NE;
    for (int e = e0 + threadIdx.x; e < e1; e += 256) {
        const unsigned src = ei[e], dst = ei[NE + e];
        const int pos = atomicAdd(&cur[dst >> BSHIFT], 1);
        binned[pos] = make_uint2((dst << 16) | src, (unsigned)e);
    }
}

__global__ __launch_bounds__(1024) void sort2_kernel(
    const uint2* __restrict__ binned, const int* __restrict__ bucketStart,
    uint2* __restrict__ sorted)
{
    __shared__ int cnt[512];
    __shared__ int pre[512];
    const int b  = blockIdx.x;
    const int lo = bucketStart[b];
    const int hi = bucketStart[b + 1];
    if (threadIdx.x < 512) cnt[threadIdx.x] = 0;
    __syncthreads();
    for (int p = lo + threadIdx.x; p < hi; p += 1024)
        atomicAdd(&cnt[(binned[p].x >> 16) & 511], 1);
    __syncthreads();
    if (threadIdx.x < 512) pre[threadIdx.x] = cnt[threadIdx.x];
    __syncthreads();
    for (int d = 1; d < 512; d <<= 1) {
        int t = (threadIdx.x < 512 && threadIdx.x >= d) ? pre[threadIdx.x - d] : 0;
        __syncthreads();
        if (threadIdx.x < 512) pre[threadIdx.x] += t;
        __syncthreads();
    }
    if (threadIdx.x < 512)
        cnt[threadIdx.x] = lo + pre[threadIdx.x] - cnt[threadIdx.x];  // exclusive cursor
    __syncthreads();
    for (int p = lo + threadIdx.x; p < hi; p += 1024) {
        const uint2 q = binned[p];
        const int pos = atomicAdd(&cnt[(q.x >> 16) & 511], 1);
        sorted[pos] = q;
    }
}

// ---------- fused edge pass over fully dst-sorted edges (R12 structure) -----
__global__ __launch_bounds__(256) void edge_fused_kernel(
    const float* __restrict__ edge_attr,
    const float* __restrict__ WE1, const float* __restrict__ bE1,
    const uint2* __restrict__ sorted,
    const float* __restrict__ Q, const float* __restrict__ K,
    const float* __restrict__ V,
    float* __restrict__ wE, float* __restrict__ den, float* __restrict__ Num)
{
    __shared__ float Elds[4][16 * ESTR];  // padded: breaks transpose-write conflicts
    __shared__ float exL[4][16 * 8];
    __shared__ int   dstL[4][16];
    const int tid  = threadIdx.x;
    const int wv   = tid >> 6;
    const int lane = tid & 63;
    const int g    = lane >> 4;
    const int rowl = lane & 15;

    bf16x4 bF[4][4];
    float  bias[4];
    #pragma unroll
    for (int cb = 0; cb < 4; ++cb) {
        const int col = rowl + 16 * cb;
        bias[cb] = bE1[col];
        #pragma unroll
        for (int ks = 0; ks < 4; ++ks) {
            bf16x4 t;
            #pragma unroll
            for (int j = 0; j < 4; ++j)
                t[j] = f2bf(WE1[(ks * 16 + g * 4 + j) * 64 + col]);
            bF[cb][ks] = t;
        }
    }

    const float inv_sqrt8 = 0.35355339059327373f;

    for (int tile = blockIdx.x; tile < (NE / 64); tile += gridDim.x) {
        const int pBase = tile * 64 + wv * 16;

        const uint2 qv  = sorted[pBase + rowl];
        const int  srcv = qv.x & 0xffff;
        const int  dstv = qv.x >> 16;
        const int  eidv = (int)qv.y;
        if (lane < 16) dstL[wv][lane] = dstv;

        bf16x4 aF[4];
        const float* ar = edge_attr + (size_t)eidv * 64 + g * 4;
        #pragma unroll
        for (int ks = 0; ks < 4; ++ks) {
            f32x4 v = __builtin_nontemporal_load(
                reinterpret_cast<const f32x4*>(ar + ks * 16));
            bf16x4 t;
            #pragma unroll
            for (int j = 0; j < 4; ++j) t[j] = f2bf(v[j]);
            aF[ks] = t;
        }

        f32x4 acc[4];
        #pragma unroll
        for (int cb = 0; cb < 4; ++cb) {
            acc[cb][0] = bias[cb]; acc[cb][1] = bias[cb];
            acc[cb][2] = bias[cb]; acc[cb][3] = bias[cb];
        }
        #pragma unroll
        for (int cb = 0; cb < 4; ++cb)
            #pragma unroll
            for (int ks = 0; ks < 4; ++ks)
                acc[cb] = __builtin_amdgcn_mfma_f32_16x16x16bf16_1k(
                    aF[ks], bF[cb][ks], acc[cb], 0, 0, 0);

        #pragma unroll
        for (int cb = 0; cb < 4; ++cb)
            #pragma unroll
            for (int r = 0; r < 4; ++r)
                Elds[wv][(g * 4 + r) * ESTR + rowl + 16 * cb] = acc[cb][r];

        #pragma unroll
        for (int qi = 0; qi < 4; ++qi) {
            const int el  = qi * 4 + g;
            const int eid = __shfl(eidv, el);
            const int src = __shfl(srcv, el);
            const int dst = __shfl(dstv, el);
            const f32x4 Kv = *reinterpret_cast<const f32x4*>(K + (size_t)src * 64 + rowl * 4);
            const f32x4 Qv = *reinterpret_cast<const f32x4*>(Q + (size_t)dst * 64 + rowl * 4);
            const f32x4 Vv = *reinterpret_cast<const f32x4*>(V + (size_t)src * 64 + rowl * 4);
            f32x4* eslot = reinterpret_cast<f32x4*>(&Elds[wv][el * ESTR + rowl * 4]);
            const f32x4 El = *eslot;
            f32x4 sc;
            #pragma unroll
            for (int j = 0; j < 4; ++j) sc[j] = Kv[j] * Qv[j] * El[j];
            __builtin_nontemporal_store(sc,
                reinterpret_cast<f32x4*>(wE + (size_t)eid * 64 + rowl * 4));
            float ss = sc[0] + sc[1] + sc[2] + sc[3];
            ss += __shfl_xor(ss, 1);
            float s = fminf(fmaxf(ss * inv_sqrt8, -CLAMP_V), CLAMP_V);
            float ex = __expf(s);
            if ((rowl & 1) == 0)
                exL[wv][el * 8 + (rowl >> 1)] = ex;
            f32x4 t;
            #pragma unroll
            for (int j = 0; j < 4; ++j) t[j] = ex * (Vv[j] + sc[j]);
            *eslot = t;
        }

        // segmented accumulation over sorted dst; one flush per run
        float accP = 0.f, accD = 0.f;
        int cur = dstL[wv][0];
        #pragma unroll
        for (int el = 0; el < 16; ++el) {
            accP += Elds[wv][el * ESTR + lane];
            accD += exL[wv][el * 8 + (lane & 7)];
            const int nxt = (el < 15) ? dstL[wv][el + 1] : -1;
            if (nxt != cur) {
                atomicAdd(&Num[(size_t)cur * 64 + lane], accP);
                if (lane < 8) atomicAdd(&den[cur * 8 + lane], accD);
                accP = 0.f; accD = 0.f; cur = nxt;
            }
        }
    }
}

__global__ __launch_bounds__(256) void finalize_kernel(
    const float* __restrict__ Num, const float* __restrict__ den,
    float* __restrict__ wV)
{
    const int i = blockIdx.x * 256 + threadIdx.x;
    if (i >= NN * 16) return;
    const int c4 = i & 15;
    const int n  = i >> 4;
    const int h  = c4 >> 1;
    const float d = den[n * 8 + h] + 1e-16f;
    f32x4 v = reinterpret_cast<const f32x4*>(Num)[i];
    v[0] /= d; v[1] /= d; v[2] /= d; v[3] /= d;
    reinterpret_cast<f32x4*>(wV)[i] = v;
}

extern "C" void kernel_launch(void* const* d_in, const int* in_sizes, int n_in,
                              void* d_out, int out_size, void* d_ws, size_t ws_size,
                              hipStream_t stream) {
    const float* x         = (const float*)d_in[0];
    const float* edge_attr = (const float*)d_in[1];
    const float* WQ        = (const float*)d_in[2];
    const float* bQ        = (const float*)d_in[3];
    const float* WK        = (const float*)d_in[4];
    const float* WVw       = (const float*)d_in[5];
    const float* WE1       = (const float*)d_in[6];
    const float* bE1       = (const float*)d_in[7];
    const int*   ei        = (const int*)d_in[8];

    float* out = (float*)d_out;
    float* wV = out;                          // [NN, 64]
    float* wE = out + (size_t)NN * 64;        // [NE, 64]

    float* Q           = (float*)d_ws;                  // [NN,64]
    float* K           = Q + (size_t)NN * 64;           // [NN,64]
    float* V           = K + (size_t)NN * 64;           // [NN,64]
    float* den         = V + (size_t)NN * 64;           // [NN,8]
    float* Num         = den + (size_t)NN * 8;          // [NN,64]
    int*   blockHist   = (int*)(Num + (size_t)NN * 64); // [NB,BPAD]
    int*   bucketTotal = blockHist + NB * BPAD;         // [BPAD]
    int*   bucketStart = bucketTotal + BPAD;            // [BPAD]
    uint2* binned      = (uint2*)(bucketStart + BPAD);  // [NE]
    uint2* sorted      = binned + NE;                   // [NE]

    hipMemsetAsync(den, 0, (size_t)NN * (8 + 64) * sizeof(float), stream);

    histproj_kernel<<<NB + PROJ_BLOCKS, 256, 0, stream>>>(
        ei, blockHist, x, WQ, bQ, WK, WVw, Q, K, V);
    scanA_kernel<<<NBUCK, 64, 0, stream>>>(blockHist, bucketTotal);
    scanB_kernel<<<1, 64, 0, stream>>>(bucketTotal, bucketStart);
    scatter1_kernel<<<NB, 256, 0, stream>>>(ei, blockHist, bucketStart, binned);
    sort2_kernel<<<NBUCK, 1024, 0, stream>>>(binned, bucketStart, sorted);
    edge_fused_kernel<<<4096, 256, 0, stream>>>(edge_attr, WE1, bE1, sorted,
                                                Q, K, V, wE, den, Num);
    finalize_kernel<<<(NN * 16 + 255) / 256, 256, 0, stream>>>(Num, den, wV);
}

// Round 16
// 353.212 us; speedup vs baseline: 1.1385x; 1.1385x over previous
//
#include <hip/hip_runtime.h>

#define NN 50000
#define NE 1600000
#define CLAMP_V 5.0f
#define NB 2048                    // phase-1 chunks
#define CH ((NE + NB - 1) / NB)    // 782 edges per chunk
#define BSHIFT 9                   // 512 nodes per bucket
#define NBUCK ((NN + (1 << BSHIFT) - 1) >> BSHIFT)   // 98
#define BPAD 128
#define ESTR 68                    // padded Elds row stride (floats)

typedef __attribute__((ext_vector_type(4))) short bf16x4;
typedef __attribute__((ext_vector_type(4))) float f32x4;

static __device__ __forceinline__ short f2bf(float x) {
    unsigned u = __builtin_bit_cast(unsigned, x);
    u += 0x7FFF + ((u >> 16) & 1);   // round-to-nearest-even
    return (short)(u >> 16);
}

__global__ __launch_bounds__(256) void proj_kernel(
    const float* __restrict__ x,
    const float* __restrict__ WQ, const float* __restrict__ bQ,
    const float* __restrict__ WK, const float* __restrict__ WVw,
    float* __restrict__ Q, float* __restrict__ K, float* __restrict__ V)
{
    __shared__ float sWQ[4096], sWK[4096], sWV[4096];
    for (int i = threadIdx.x; i < 4096; i += 256) {
        sWQ[i] = WQ[i]; sWK[i] = WK[i]; sWV[i] = WVw[i];
    }
    __syncthreads();
    const int col = threadIdx.x & 63;
    const int nl  = threadIdx.x >> 6;
    const float bq = bQ[col];
    for (int node = blockIdx.x * 4 + nl; node < NN; node += gridDim.x * 4) {
        const float* xr = x + (size_t)node * 64;
        float aq = 0.f, ak = 0.f, av = 0.f;
        #pragma unroll
        for (int j = 0; j < 64; ++j) {
            float xv = xr[j];
            aq = fmaf(xv, sWQ[j*64+col], aq);
            ak = fmaf(xv, sWK[j*64+col], ak);
            av = fmaf(xv, sWV[j*64+col], av);
        }
        Q[(size_t)node*64+col] = aq + bq;
        K[(size_t)node*64+col] = ak;
        V[(size_t)node*64+col] = av;
    }
}

// ---------- phase 1: coarse bin by dst>>9 ----------------------------------
__global__ __launch_bounds__(256) void hist1_kernel(
    const int* __restrict__ ei, int* __restrict__ blockHist)
{
    __shared__ int h[BPAD];
    if (threadIdx.x < BPAD) h[threadIdx.x] = 0;
    __syncthreads();
    const int b  = blockIdx.x;
    const int e0 = b * CH;
    const int e1 = (e0 + CH < NE) ? e0 + CH : NE;
    for (int e = e0 + threadIdx.x; e < e1; e += 256)
        atomicAdd(&h[ei[NE + e] >> BSHIFT], 1);
    __syncthreads();
    if (threadIdx.x < NBUCK) blockHist[b * BPAD + threadIdx.x] = h[threadIdx.x];
}

__global__ __launch_bounds__(64) void scanA_kernel(
    int* __restrict__ blockHist, int* __restrict__ bucketTotal)
{
    const int k    = blockIdx.x;
    const int lane = threadIdx.x;
    int running = 0;
    for (int c = 0; c < NB; c += 64) {
        int v = blockHist[(c + lane) * BPAD + k];
        int incl = v;
        #pragma unroll
        for (int d = 1; d < 64; d <<= 1) {
            int t = __shfl_up(incl, d);
            if (lane >= d) incl += t;
        }
        blockHist[(c + lane) * BPAD + k] = running + (incl - v);
        running += __shfl(incl, 63);
    }
    if (lane == 0) bucketTotal[k] = running;
}

// wave-parallel exclusive scan of the 98 bucket totals
__global__ __launch_bounds__(64) void scanB_kernel(
    const int* __restrict__ bucketTotal, int* __restrict__ bucketStart)
{
    const int lane = threadIdx.x;
    int carry = 0;
    for (int base = 0; base <= NBUCK; base += 64) {
        const int idx = base + lane;
        int v = (idx < NBUCK) ? bucketTotal[idx] : 0;
        int incl = v;
        #pragma unroll
        for (int d = 1; d < 64; d <<= 1) {
            int t = __shfl_up(incl, d);
            if (lane >= d) incl += t;
        }
        if (idx <= NBUCK) bucketStart[idx] = carry + incl - v;
        carry += __shfl(incl, 63);
    }
}

__global__ __launch_bounds__(256) void scatter1_kernel(
    const int* __restrict__ ei, const int* __restrict__ blockHist,
    const int* __restrict__ bucketStart, uint2* __restrict__ binned)
{
    __shared__ int cur[BPAD];
    const int b = blockIdx.x;
    if (threadIdx.x < NBUCK)
        cur[threadIdx.x] = bucketStart[threadIdx.x] + blockHist[b * BPAD + threadIdx.x];
    __syncthreads();
    const int e0 = b * CH;
    const int e1 = (e0 + CH < NE) ? e0 + CH : NE;
    for (int e = e0 + threadIdx.x; e < e1; e += 256) {
        const unsigned src = ei[e], dst = ei[NE + e];
        const int pos = atomicAdd(&cur[dst >> BSHIFT], 1);
        binned[pos] = make_uint2((dst << 16) | src, (unsigned)e);
    }
}

// ---------- phase 2: per-bucket counting sort (L2-local window) -------------
__global__ __launch_bounds__(1024) void sort2_kernel(
    const uint2* __restrict__ binned, const int* __restrict__ bucketStart,
    uint2* __restrict__ sorted)
{
    __shared__ int cnt[512];
    __shared__ int pre[512];
    const int b  = blockIdx.x;
    const int lo = bucketStart[b];
    const int hi = bucketStart[b + 1];
    if (threadIdx.x < 512) cnt[threadIdx.x] = 0;
    __syncthreads();
    for (int p = lo + threadIdx.x; p < hi; p += 1024)
        atomicAdd(&cnt[(binned[p].x >> 16) & 511], 1);
    __syncthreads();
    if (threadIdx.x < 512) pre[threadIdx.x] = cnt[threadIdx.x];
    __syncthreads();
    for (int d = 1; d < 512; d <<= 1) {
        int t = (threadIdx.x < 512 && threadIdx.x >= d) ? pre[threadIdx.x - d] : 0;
        __syncthreads();
        if (threadIdx.x < 512) pre[threadIdx.x] += t;
        __syncthreads();
    }
    if (threadIdx.x < 512)
        cnt[threadIdx.x] = lo + pre[threadIdx.x] - cnt[threadIdx.x];  // exclusive cursor
    __syncthreads();
    for (int p = lo + threadIdx.x; p < hi; p += 1024) {
        const uint2 q = binned[p];
        const int pos = atomicAdd(&cnt[(q.x >> 16) & 511], 1);
        sorted[pos] = q;
    }
}

// ---------- fused edge pass over fully dst-sorted edges ---------------------
__global__ __launch_bounds__(256) void edge_fused_kernel(
    const float* __restrict__ edge_attr,
    const float* __restrict__ WE1, const float* __restrict__ bE1,
    const uint2* __restrict__ sorted,
    const float* __restrict__ Q, const float* __restrict__ K,
    const float* __restrict__ V,
    float* __restrict__ wE, float* __restrict__ den, float* __restrict__ Num)
{
    __shared__ float Elds[4][16 * ESTR];  // padded: conflict-free transpose write
    __shared__ float exL[4][16 * 8];
    __shared__ int   dstL[4][16];
    const int tid  = threadIdx.x;
    const int wv   = tid >> 6;
    const int lane = tid & 63;
    const int g    = lane >> 4;
    const int rowl = lane & 15;

    bf16x4 bF[4][4];
    float  bias[4];
    #pragma unroll
    for (int cb = 0; cb < 4; ++cb) {
        const int col = rowl + 16 * cb;
        bias[cb] = bE1[col];
        #pragma unroll
        for (int ks = 0; ks < 4; ++ks) {
            bf16x4 t;
            #pragma unroll
            for (int j = 0; j < 4; ++j)
                t[j] = f2bf(WE1[(ks * 16 + g * 4 + j) * 64 + col]);
            bF[cb][ks] = t;
        }
    }

    const float inv_sqrt8 = 0.35355339059327373f;

    for (int tile = blockIdx.x; tile < (NE / 64); tile += gridDim.x) {
        const int pBase = tile * 64 + wv * 16;

        const uint2 qv  = sorted[pBase + rowl];
        const int  srcv = qv.x & 0xffff;
        const int  dstv = qv.x >> 16;
        const int  eidv = (int)qv.y;
        if (lane < 16) dstL[wv][lane] = dstv;

        bf16x4 aF[4];
        const float* ar = edge_attr + (size_t)eidv * 64 + g * 4;
        #pragma unroll
        for (int ks = 0; ks < 4; ++ks) {
            f32x4 v = __builtin_nontemporal_load(
                reinterpret_cast<const f32x4*>(ar + ks * 16));
            bf16x4 t;
            #pragma unroll
            for (int j = 0; j < 4; ++j) t[j] = f2bf(v[j]);
            aF[ks] = t;
        }

        f32x4 acc[4];
        #pragma unroll
        for (int cb = 0; cb < 4; ++cb) {
            acc[cb][0] = bias[cb]; acc[cb][1] = bias[cb];
            acc[cb][2] = bias[cb]; acc[cb][3] = bias[cb];
        }
        #pragma unroll
        for (int cb = 0; cb < 4; ++cb)
            #pragma unroll
            for (int ks = 0; ks < 4; ++ks)
                acc[cb] = __builtin_amdgcn_mfma_f32_16x16x16bf16_1k(
                    aF[ks], bF[cb][ks], acc[cb], 0, 0, 0);

        #pragma unroll
        for (int cb = 0; cb < 4; ++cb)
            #pragma unroll
            for (int r = 0; r < 4; ++r)
                Elds[wv][(g * 4 + r) * ESTR + rowl + 16 * cb] = acc[cb][r];

        #pragma unroll
        for (int qi = 0; qi < 4; ++qi) {
            const int el  = qi * 4 + g;
            const int eid = __shfl(eidv, el);
            const int src = __shfl(srcv, el);
            const int dst = __shfl(dstv, el);
            const f32x4 Kv = *reinterpret_cast<const f32x4*>(K + (size_t)src * 64 + rowl * 4);
            const f32x4 Qv = *reinterpret_cast<const f32x4*>(Q + (size_t)dst * 64 + rowl * 4);
            const f32x4 Vv = *reinterpret_cast<const f32x4*>(V + (size_t)src * 64 + rowl * 4);
            f32x4* eslot = reinterpret_cast<f32x4*>(&Elds[wv][el * ESTR + rowl * 4]);
            const f32x4 El = *eslot;
            f32x4 sc;
            #pragma unroll
            for (int j = 0; j < 4; ++j) sc[j] = Kv[j] * Qv[j] * El[j];
            __builtin_nontemporal_store(sc,
                reinterpret_cast<f32x4*>(wE + (size_t)eid * 64 + rowl * 4));
            float ss = sc[0] + sc[1] + sc[2] + sc[3];
            ss += __shfl_xor(ss, 1);
            float s = fminf(fmaxf(ss * inv_sqrt8, -CLAMP_V), CLAMP_V);
            float ex = __expf(s);
            if ((rowl & 1) == 0)
                exL[wv][el * 8 + (rowl >> 1)] = ex;
            f32x4 t;
            #pragma unroll
            for (int j = 0; j < 4; ++j) t[j] = ex * (Vv[j] + sc[j]);
            *eslot = t;
        }

        // segmented accumulation over sorted dst; one flush per run
        float accP = 0.f, accD = 0.f;
        int cur = dstL[wv][0];
        #pragma unroll
        for (int el = 0; el < 16; ++el) {
            accP += Elds[wv][el * ESTR + lane];
            accD += exL[wv][el * 8 + (lane & 7)];
            const int nxt = (el < 15) ? dstL[wv][el + 1] : -1;
            if (nxt != cur) {
                atomicAdd(&Num[(size_t)cur * 64 + lane], accP);
                if (lane < 8) atomicAdd(&den[cur * 8 + lane], accD);
                accP = 0.f; accD = 0.f; cur = nxt;
            }
        }
    }
}

__global__ __launch_bounds__(256) void finalize_kernel(
    const float* __restrict__ Num, const float* __restrict__ den,
    float* __restrict__ wV)
{
    const int i = blockIdx.x * 256 + threadIdx.x;
    if (i >= NN * 16) return;
    const int c4 = i & 15;
    const int n  = i >> 4;
    const int h  = c4 >> 1;
    const float d = den[n * 8 + h] + 1e-16f;
    f32x4 v = reinterpret_cast<const f32x4*>(Num)[i];
    v[0] /= d; v[1] /= d; v[2] /= d; v[3] /= d;
    reinterpret_cast<f32x4*>(wV)[i] = v;
}

extern "C" void kernel_launch(void* const* d_in, const int* in_sizes, int n_in,
                              void* d_out, int out_size, void* d_ws, size_t ws_size,
                              hipStream_t stream) {
    const float* x         = (const float*)d_in[0];
    const float* edge_attr = (const float*)d_in[1];
    const float* WQ        = (const float*)d_in[2];
    const float* bQ        = (const float*)d_in[3];
    const float* WK        = (const float*)d_in[4];
    const float* WVw       = (const float*)d_in[5];
    const float* WE1       = (const float*)d_in[6];
    const float* bE1       = (const float*)d_in[7];
    const int*   ei        = (const int*)d_in[8];

    float* out = (float*)d_out;
    float* wV = out;                          // [NN, 64]
    float* wE = out + (size_t)NN * 64;        // [NE, 64]

    float* Q           = (float*)d_ws;                  // [NN,64]
    float* K           = Q + (size_t)NN * 64;           // [NN,64]
    float* V           = K + (size_t)NN * 64;           // [NN,64]
    float* den         = V + (size_t)NN * 64;           // [NN,8]
    float* Num         = den + (size_t)NN * 8;          // [NN,64]
    int*   blockHist   = (int*)(Num + (size_t)NN * 64); // [NB,BPAD]
    int*   bucketTotal = blockHist + NB * BPAD;         // [BPAD]
    int*   bucketStart = bucketTotal + BPAD;            // [BPAD]
    uint2* binned      = (uint2*)(bucketStart + BPAD);  // [NE]
    uint2* sorted      = binned + NE;                   // [NE]

    hipMemsetAsync(den, 0, (size_t)NN * (8 + 64) * sizeof(float), stream);

    hist1_kernel<<<NB, 256, 0, stream>>>(ei, blockHist);
    scanA_kernel<<<NBUCK, 64, 0, stream>>>(blockHist, bucketTotal);
    scanB_kernel<<<1, 64, 0, stream>>>(bucketTotal, bucketStart);
    scatter1_kernel<<<NB, 256, 0, stream>>>(ei, blockHist, bucketStart, binned);
    sort2_kernel<<<NBUCK, 1024, 0, stream>>>(binned, bucketStart, sorted);
    proj_kernel<<<1024, 256, 0, stream>>>(x, WQ, bQ, WK, WVw, Q, K, V);
    edge_fused_kernel<<<2048, 256, 0, stream>>>(edge_attr, WE1, bE1, sorted,
                                                Q, K, V, wE, den, Num);
    finalize_kernel<<<(NN * 16 + 255) / 256, 256, 0, stream>>>(Num, den, wV);
}